// Round 15
// baseline (175.799 us; speedup 1.0000x reference)
//
#include <hip/hip_runtime.h>

#define NGRAPH 16384
#define NNODE  32
#define EMB    64
#define HIDDIM 2048
#define ETOT   4194304      // NTOT * 8
#define EPG    256          // edges per graph (contiguous block per graph)

typedef __attribute__((ext_vector_type(8))) short bf16x8_t;
typedef __attribute__((ext_vector_type(8))) unsigned short u16x8_t;
typedef __attribute__((ext_vector_type(4))) float f32x4_t;

__device__ __forceinline__ unsigned short f2bf(float v) {
  unsigned int u = __float_as_uint(v);
  u += 0x7fffu + ((u >> 16) & 1u);
  return (unsigned short)(u >> 16);
}
__device__ __forceinline__ float bf2f(unsigned short u) {
  return __uint_as_float(((unsigned int)u) << 16);
}
__device__ __forceinline__ unsigned int cvtpk(float lo, float hi) {
  unsigned int r;
  asm("v_cvt_pk_bf16_f32 %0, %1, %2" : "=v"(r) : "v"(lo), "v"(hi));
  return r;
}
__device__ __forceinline__ bf16x8_t pack8(float4 a, float4 b) {
  union { unsigned int u[4]; bf16x8_t v; } r;
  r.u[0] = cvtpk(a.x, a.y); r.u[1] = cvtpk(a.z, a.w);
  r.u[2] = cvtpk(b.x, b.y); r.u[3] = cvtpk(b.z, b.w);
  return r.v;
}

#define GLDS(SRC, DST)                                                          \
  __builtin_amdgcn_global_load_lds(                                             \
      (const __attribute__((address_space(1))) void*)(SRC),                     \
      (__attribute__((address_space(3))) void*)(DST), 16, 0, 0)

// ---------------------------------------------------------------------------
// Kernel 1 (merged front): blocks [0,4096) = fused GCNConv+ReLU (wave-per-
// graph); blocks [4096,6144) = W1 fp32->bf16 col-permuted (k'=feat*32+node).
// ---------------------------------------------------------------------------
__global__ __launch_bounds__(256, 4) void front_kernel(const float* __restrict__ x,
                                                       const float* __restrict__ Wc,
                                                       const float* __restrict__ bc,
                                                       const int* __restrict__ ei,
                                                       unsigned short* __restrict__ abf,
                                                       const float* __restrict__ W1,
                                                       unsigned short* __restrict__ W1b) {
  __shared__ __align__(16) char smem[40960];     // gcn: 4 waves x 10240B; cvt: 8KB

  if (blockIdx.x >= 4096) {
    // ---------------- cvt_w1 branch ----------------
    float* row = (float*)smem;
    const int r = blockIdx.x - 4096, t = threadIdx.x;
    const float4* p = (const float4*)(W1 + (size_t)r * HIDDIM);
    *(float4*)&row[t * 8]     = p[t * 2];
    *(float4*)&row[t * 8 + 4] = p[t * 2 + 1];
    __syncthreads();
    const int feat = t >> 2, nb = (t & 3) * 8;
    u16x8_t o;
    #pragma unroll
    for (int j = 0; j < 8; ++j) o[j] = f2bf(row[(nb + j) * 64 + feat]);
    *(u16x8_t*)(W1b + (size_t)r * HIDDIM + t * 8) = o;
    return;
  }

  // ---------------- gcn branch ----------------
  const int wv = threadIdx.x >> 6, lane = threadIdx.x & 63;
  const int g = blockIdx.x * 4 + wv;
  char* my = smem + wv * 10240;
  unsigned int*   adjcnt = (unsigned int*)my;            // u32 [32][32], 4096B
  unsigned short* adjb   = (unsigned short*)my;          // bf16 [32][40] (overlays)
  unsigned short* outT   = (unsigned short*)my;          // bf16 [64][40] (overlays)
  unsigned short* hT     = (unsigned short*)(my + 5120); // bf16 [64][40]
  const int lr = lane & 15, lk = lane >> 4;

  const float* xg = x + (size_t)g * (NNODE * EMB);
  float4 xr[2][2][2];
  #pragma unroll
  for (int mt = 0; mt < 2; ++mt)
    #pragma unroll
    for (int kk = 0; kk < 2; ++kk) {
      const float* p = xg + (mt * 16 + lr) * EMB + kk * 32 + lk * 8;
      xr[mt][kk][0] = *(const float4*)p;
      xr[mt][kk][1] = *(const float4*)(p + 4);
    }

  int sl[4], dl[4];
  #pragma unroll
  for (int j = 0; j < 4; ++j) {
    sl[j] = ei[(size_t)g * EPG + j * 64 + lane] - g * NNODE;
    dl[j] = ei[(size_t)ETOT + (size_t)g * EPG + j * 64 + lane] - g * NNODE;
  }

  {
    uint4 z = {0u, 0u, 0u, 0u};
    #pragma unroll
    for (int i = 0; i < 4; ++i) *(uint4*)&adjcnt[lane * 16 + i * 4] = z;
  }
  asm volatile("" ::: "memory");
  #pragma unroll
  for (int j = 0; j < 4; ++j) atomicAdd(&adjcnt[dl[j] * 32 + sl[j]], 1u);
  asm volatile("" ::: "memory");

  const int rr = lane >> 1, hh = lane & 1;
  uint4 c[4];
  unsigned int cs = 0;
  #pragma unroll
  for (int i = 0; i < 4; ++i) {
    c[i] = *(const uint4*)&adjcnt[rr * 32 + hh * 16 + i * 4];
    cs += c[i].x + c[i].y + c[i].z + c[i].w;
  }
  cs += (unsigned int)__shfl_xor((int)cs, 1);
  const float dinvr = rsqrtf(1.0f + (float)cs);
  asm volatile("" ::: "memory");
  {
    float vals[16];
    #pragma unroll
    for (int i = 0; i < 4; ++i) {
      const unsigned int cc[4] = {c[i].x, c[i].y, c[i].z, c[i].w};
      #pragma unroll
      for (int e = 0; e < 4; ++e) {
        const int s = hh * 16 + i * 4 + e;
        const float ds = __shfl(dinvr, s * 2);
        const float cnt = (float)cc[e] + ((s == rr) ? 1.0f : 0.0f);
        vals[i * 4 + e] = cnt * dinvr * ds;
      }
    }
    union { unsigned int u[8]; u16x8_t v[2]; } pk;
    #pragma unroll
    for (int i = 0; i < 8; ++i) pk.u[i] = cvtpk(vals[2 * i], vals[2 * i + 1]);
    *(u16x8_t*)&adjb[rr * 40 + hh * 16]     = pk.v[0];
    *(u16x8_t*)&adjb[rr * 40 + hh * 16 + 8] = pk.v[1];
  }

  bf16x8_t xa[2][2];
  #pragma unroll
  for (int mt = 0; mt < 2; ++mt)
    #pragma unroll
    for (int kk = 0; kk < 2; ++kk) xa[mt][kk] = pack8(xr[mt][kk][0], xr[mt][kk][1]);
  f32x4_t hc[2][4];
  #pragma unroll
  for (int mt = 0; mt < 2; ++mt)
    #pragma unroll
    for (int nt = 0; nt < 4; ++nt) hc[mt][nt] = (f32x4_t){0.f, 0.f, 0.f, 0.f};
  #pragma unroll
  for (int nt = 0; nt < 4; ++nt)
    #pragma unroll
    for (int kk = 0; kk < 2; ++kk) {
      const float* p = Wc + (nt * 16 + lr) * EMB + kk * 32 + lk * 8;
      const bf16x8_t wb = pack8(*(const float4*)p, *(const float4*)(p + 4));
      #pragma unroll
      for (int mt = 0; mt < 2; ++mt)
        hc[mt][nt] = __builtin_amdgcn_mfma_f32_16x16x32_bf16(xa[mt][kk], wb, hc[mt][nt], 0, 0, 0);
    }
  #pragma unroll
  for (int mt = 0; mt < 2; ++mt)
    #pragma unroll
    for (int nt = 0; nt < 4; ++nt) {
      uint2 pk;
      pk.x = cvtpk(hc[mt][nt][0], hc[mt][nt][1]);
      pk.y = cvtpk(hc[mt][nt][2], hc[mt][nt][3]);
      *(uint2*)&hT[(nt * 16 + lr) * 40 + mt * 16 + lk * 4] = pk;
    }
  asm volatile("" ::: "memory");

  bf16x8_t aj[2];
  #pragma unroll
  for (int mt = 0; mt < 2; ++mt)
    aj[mt] = *(const bf16x8_t*)&adjb[(mt * 16 + lr) * 40 + lk * 8];
  f32x4_t oc[2][4];
  #pragma unroll
  for (int mt = 0; mt < 2; ++mt)
    #pragma unroll
    for (int nt = 0; nt < 4; ++nt) oc[mt][nt] = (f32x4_t){0.f, 0.f, 0.f, 0.f};
  #pragma unroll
  for (int nt = 0; nt < 4; ++nt) {
    const bf16x8_t hb = *(const bf16x8_t*)&hT[(nt * 16 + lr) * 40 + lk * 8];
    #pragma unroll
    for (int mt = 0; mt < 2; ++mt)
      oc[mt][nt] = __builtin_amdgcn_mfma_f32_16x16x32_bf16(aj[mt], hb, oc[mt][nt], 0, 0, 0);
  }
  asm volatile("" ::: "memory");

  #pragma unroll
  for (int nt = 0; nt < 4; ++nt) {
    const float bcv = bc[nt * 16 + lr];
    #pragma unroll
    for (int mt = 0; mt < 2; ++mt) {
      float v0 = fmaxf(oc[mt][nt][0] + bcv, 0.0f);
      float v1 = fmaxf(oc[mt][nt][1] + bcv, 0.0f);
      float v2 = fmaxf(oc[mt][nt][2] + bcv, 0.0f);
      float v3 = fmaxf(oc[mt][nt][3] + bcv, 0.0f);
      uint2 pk;
      pk.x = cvtpk(v0, v1);
      pk.y = cvtpk(v2, v3);
      *(uint2*)&outT[(nt * 16 + lr) * 40 + mt * 16 + lk * 4] = pk;
    }
  }
  asm volatile("" ::: "memory");

  unsigned short* og = abf + (size_t)g * HIDDIM;
  #pragma unroll
  for (int j = 0; j < 4; ++j) {
    const int e = lane * 8 + j * 512;
    const int feat = e >> 5, nb = e & 31;
    *(u16x8_t*)(og + e) = *(const u16x8_t*)&outT[feat * 40 + nb];
  }
}

// ---------------------------------------------------------------------------
// Kernel 2: lin1 GEMM + FUSED lin2 partial dots, NO ATOMICS.
// Single-phase-per-tile schedule with TRIPLE-BUFFERED B (A dbuf x2 32KB,
// B x3 32KB = 160KB LDS). Per tile t: {24 ds_reads (A0+A1+B) || stage A(t+1),
// B(t+2) -> lgkm0 -> vmcnt(4) [vmcnt(0) at t>=30] -> barrier -> 64 MFMA}.
// No same-phase WAR: A(t+1) targets other dbuf; B(t+2) targets buf (t+2)%3.
// Barriers: 33/block (vs r14's 129). Read sets/acc mapping/epilogue unchanged.
// ---------------------------------------------------------------------------
__global__ __launch_bounds__(512, 1) void lin1_kernel(const unsigned short* __restrict__ A,
                                                      const unsigned short* __restrict__ Bw,
                                                      const float* __restrict__ b1,
                                                      const float* __restrict__ W2,
                                                      float2* __restrict__ part) {
  __shared__ __align__(16) unsigned short sh[81920];   // 160 KB: A 2x16384, B 3x16384

  const int bid = blockIdx.x;
  const int xcd = bid & 7;
  const int g = bid >> 3;                  // 0..63 within XCD
  const int bm = xcd * 8 + (g >> 3);
  const int bn = g & 7;

  const int tid = threadIdx.x;
  const int lane = tid & 63, w = tid >> 6;
  const int wm = w >> 2, wn = w & 3;       // 2 M-waves x 4 N-waves
  const int lr = lane & 15, lk = lane >> 4;

  const int r0 = tid >> 3;
  const int kge = ((((tid & 7) * 16) ^ ((r0 & 7) << 4)) >> 1);  // swizzled elem
  const unsigned short* gA = A  + (size_t)(bm * 256 + r0) * HIDDIM + kge;
  const unsigned short* gB = Bw + (size_t)(bn * 256 + r0) * HIDDIM + kge;

  auto stageA = [&](int d, int half, int tile) {
    const unsigned short* s = gA + (size_t)(half * 128) * HIDDIM + tile * 64;
    unsigned short* l = &sh[d * 16384 + half * 8192 + tid * 8];
    GLDS(s, l);
    GLDS(s + (size_t)64 * HIDDIM, l + 4096);
  };
  auto stageB = [&](int cb, int half, int tile) {
    const unsigned short* s = gB + (size_t)(half * 128) * HIDDIM + tile * 64;
    unsigned short* l = &sh[32768 + cb * 16384 + half * 8192 + tid * 8];
    GLDS(s, l);
    GLDS(s + (size_t)64 * HIDDIM, l + 4096);
  };

  const int arow = wm * 8192 + lr * 64;
  const int brow = (wn >> 1) * 8192 + ((wn & 1) * 64 + lr) * 64;
  int eoff[2];
  eoff[0] = (lk * 8) ^ ((lr & 7) << 3);
  eoff[1] = (32 + lk * 8) ^ ((lr & 7) << 3);

  f32x4_t acc[8][4];
  #pragma unroll
  for (int i = 0; i < 8; ++i)
    #pragma unroll
    for (int j = 0; j < 4; ++j) acc[i][j] = (f32x4_t){0.f, 0.f, 0.f, 0.f};

  // ---- prologue: A(0)->d0, B(0)->c0, B(1)->c1; gate vmcnt(4); barrier
  stageA(0, 0, 0); stageA(0, 1, 0);
  stageB(0, 0, 0); stageB(0, 1, 0);
  stageB(1, 0, 1); stageB(1, 1, 1);
  asm volatile("s_waitcnt vmcnt(4)" ::: "memory");
  __builtin_amdgcn_sched_barrier(0);
  __builtin_amdgcn_s_barrier();

  int cb = 0;   // B buffer for tile t
  for (int t = 0; t < 32; ++t) {
    const int abase = (t & 1) * 16384;
    const int bbase = 32768 + cb * 16384;

    // ---- reads: all A frags (A0+A1) + all B frags of tile t
    bf16x8_t af[8][2], bv[4][2];
    #pragma unroll
    for (int mi = 0; mi < 8; ++mi) {
      af[mi][0] = *(const bf16x8_t*)&sh[abase + arow + mi * 1024 + eoff[0]];
      af[mi][1] = *(const bf16x8_t*)&sh[abase + arow + mi * 1024 + eoff[1]];
    }
    #pragma unroll
    for (int ni = 0; ni < 4; ++ni) {
      bv[ni][0] = *(const bf16x8_t*)&sh[bbase + brow + ni * 1024 + eoff[0]];
      bv[ni][1] = *(const bf16x8_t*)&sh[bbase + brow + ni * 1024 + eoff[1]];
    }

    // ---- stages: A(t+1) first (drained by this gate), then B(t+2)
    if (t < 31) {
      const int dn = (t + 1) & 1;
      stageA(dn, 0, t + 1);
      stageA(dn, 1, t + 1);
    }
    if (t < 30) {
      const int c2 = (cb >= 1) ? cb - 1 : 2;   // (t+2)%3
      stageB(c2, 0, t + 2);
      stageB(c2, 1, t + 2);
    }

    asm volatile("s_waitcnt lgkmcnt(0)" ::: "memory");
    if (t < 30) { asm volatile("s_waitcnt vmcnt(4)" ::: "memory"); }
    else        { asm volatile("s_waitcnt vmcnt(0)" ::: "memory"); }
    __builtin_amdgcn_sched_barrier(0);
    __builtin_amdgcn_s_barrier();

    __builtin_amdgcn_s_setprio(1);
    #pragma unroll
    for (int kk = 0; kk < 2; ++kk)
      #pragma unroll
      for (int mi = 0; mi < 8; ++mi)
        #pragma unroll
        for (int ni = 0; ni < 4; ++ni)
          acc[mi][ni] = __builtin_amdgcn_mfma_f32_16x16x32_bf16(af[mi][kk], bv[ni][kk], acc[mi][ni], 0, 0, 0);
    __builtin_amdgcn_s_setprio(0);

    cb = (cb == 2) ? 0 : cb + 1;
  }

  // ---- fused epilogue (no atomics): relu(acc+b1).W2 -> lr shfl-reduce ->
  // cross-wn LDS reduce -> coalesced float2 partial store per block.
  const int ccol0 = bn * 256 + wn * 64 + lr;
  float b1v[4], w2a[4], w2b[4];
  #pragma unroll
  for (int ni = 0; ni < 4; ++ni) {
    b1v[ni] = b1[ccol0 + ni * 16];
    w2a[ni] = W2[ccol0 + ni * 16];
    w2b[ni] = W2[HIDDIM + ccol0 + ni * 16];
  }
  float2* pl = (float2*)sh;   // [256][4] float2 = 8KB; safe overlay
  #pragma unroll
  for (int mi = 0; mi < 8; ++mi)
    #pragma unroll
    for (int r = 0; r < 4; ++r) {
      float s0 = 0.0f, s1 = 0.0f;
      #pragma unroll
      for (int ni = 0; ni < 4; ++ni) {
        const float v = fmaxf(acc[mi][ni][r] + b1v[ni], 0.0f);
        s0 = fmaf(v, w2a[ni], s0);
        s1 = fmaf(v, w2b[ni], s1);
      }
      #pragma unroll
      for (int off = 1; off < 16; off <<= 1) {
        s0 += __shfl_xor(s0, off);
        s1 += __shfl_xor(s1, off);
      }
      if (lr == 0) {
        const int rowLocal = wm * 128 + mi * 16 + lk * 4 + r;
        float2 v2; v2.x = s0; v2.y = s1;
        pl[rowLocal * 4 + wn] = v2;
      }
    }
  __syncthreads();
  if (tid < 256) {
    const float2 p0 = pl[tid * 4 + 0];
    const float2 p1 = pl[tid * 4 + 1];
    const float2 p2 = pl[tid * 4 + 2];
    const float2 p3 = pl[tid * 4 + 3];
    float2 o;
    o.x = (p0.x + p1.x) + (p2.x + p3.x);
    o.y = (p0.y + p1.y) + (p2.y + p3.y);
    part[(size_t)bn * NGRAPH + bm * 256 + tid] = o;
  }
}

// ---------------------------------------------------------------------------
// Kernel 3: sum 8 bn-partials + b2 -> softmax
// ---------------------------------------------------------------------------
__global__ __launch_bounds__(256) void softmax_kernel(const float2* __restrict__ part,
                                                      const float* __restrict__ b2,
                                                      float* __restrict__ out) {
  const int i = blockIdx.x * 256 + threadIdx.x;   // graph id
  float s0 = 0.0f, s1 = 0.0f;
  #pragma unroll
  for (int bn = 0; bn < 8; ++bn) {
    const float2 p = part[(size_t)bn * NGRAPH + i];
    s0 += p.x; s1 += p.y;
  }
  const float l0 = s0 + b2[0];
  const float l1 = s1 + b2[1];
  const float mx = fmaxf(l0, l1);
  const float e0 = expf(l0 - mx);
  const float e1 = expf(l1 - mx);
  const float inv = 1.0f / (e0 + e1);
  float2 o;
  o.x = e0 * inv;
  o.y = e1 * inv;
  *((float2*)out + i) = o;
}

// ---------------------------------------------------------------------------
extern "C" void kernel_launch(void* const* d_in, const int* in_sizes, int n_in,
                              void* d_out, int out_size, void* d_ws, size_t ws_size,
                              hipStream_t stream) {
  const float* x  = (const float*)d_in[0];
  const float* Wc = (const float*)d_in[1];
  const float* bc = (const float*)d_in[2];
  const float* W1 = (const float*)d_in[3];
  const float* b1 = (const float*)d_in[4];
  const float* W2 = (const float*)d_in[5];
  const float* b2 = (const float*)d_in[6];
  const int* ei   = (const int*)d_in[7];

  // workspace: [0,64MB) Abf bf16 (graph-transposed); [64,72MB) W1bf bf16
  // (col-permuted); [72MB, +1MB) part fp32x2 [8][16384]
  unsigned short* Abf  = (unsigned short*)d_ws;
  unsigned short* W1bf = (unsigned short*)((char*)d_ws + (size_t)67108864);
  float2*         part = (float2*)((char*)d_ws + (size_t)75497472);

  front_kernel<<<dim3(6144), dim3(256), 0, stream>>>(x, Wc, bc, ei, Abf, W1, W1bf);
  lin1_kernel<<<dim3(512), dim3(512), 0, stream>>>(Abf, W1bf, b1, W2, part);
  softmax_kernel<<<dim3(64), dim3(256), 0, stream>>>(part, b2, (float*)d_out);
}

// Round 16
// 165.816 us; speedup vs baseline: 1.0602x; 1.0602x over previous
//
#include <hip/hip_runtime.h>

#define NGRAPH 16384
#define NNODE  32
#define EMB    64
#define HIDDIM 2048
#define ETOT   4194304      // NTOT * 8
#define EPG    256          // edges per graph (contiguous block per graph)

typedef __attribute__((ext_vector_type(8))) short bf16x8_t;
typedef __attribute__((ext_vector_type(8))) unsigned short u16x8_t;
typedef __attribute__((ext_vector_type(4))) float f32x4_t;

__device__ __forceinline__ unsigned short f2bf(float v) {
  unsigned int u = __float_as_uint(v);
  u += 0x7fffu + ((u >> 16) & 1u);
  return (unsigned short)(u >> 16);
}
__device__ __forceinline__ float bf2f(unsigned short u) {
  return __uint_as_float(((unsigned int)u) << 16);
}
__device__ __forceinline__ unsigned int cvtpk(float lo, float hi) {
  unsigned int r;
  asm("v_cvt_pk_bf16_f32 %0, %1, %2" : "=v"(r) : "v"(lo), "v"(hi));
  return r;
}
__device__ __forceinline__ bf16x8_t pack8(float4 a, float4 b) {
  union { unsigned int u[4]; bf16x8_t v; } r;
  r.u[0] = cvtpk(a.x, a.y); r.u[1] = cvtpk(a.z, a.w);
  r.u[2] = cvtpk(b.x, b.y); r.u[3] = cvtpk(b.z, b.w);
  return r.v;
}

#define GLDS(SRC, DST)                                                          \
  __builtin_amdgcn_global_load_lds(                                             \
      (const __attribute__((address_space(1))) void*)(SRC),                     \
      (__attribute__((address_space(3))) void*)(DST), 16, 0, 0)

// ---------------------------------------------------------------------------
// Kernel 1 (merged front): blocks [0,4096) = fused GCNConv+ReLU (wave-per-
// graph); blocks [4096,6144) = W1 fp32->bf16 col-permuted (k'=feat*32+node).
// ---------------------------------------------------------------------------
__global__ __launch_bounds__(256, 4) void front_kernel(const float* __restrict__ x,
                                                       const float* __restrict__ Wc,
                                                       const float* __restrict__ bc,
                                                       const int* __restrict__ ei,
                                                       unsigned short* __restrict__ abf,
                                                       const float* __restrict__ W1,
                                                       unsigned short* __restrict__ W1b) {
  __shared__ __align__(16) char smem[40960];     // gcn: 4 waves x 10240B; cvt: 8KB

  if (blockIdx.x >= 4096) {
    // ---------------- cvt_w1 branch ----------------
    float* row = (float*)smem;
    const int r = blockIdx.x - 4096, t = threadIdx.x;
    const float4* p = (const float4*)(W1 + (size_t)r * HIDDIM);
    *(float4*)&row[t * 8]     = p[t * 2];
    *(float4*)&row[t * 8 + 4] = p[t * 2 + 1];
    __syncthreads();
    const int feat = t >> 2, nb = (t & 3) * 8;
    u16x8_t o;
    #pragma unroll
    for (int j = 0; j < 8; ++j) o[j] = f2bf(row[(nb + j) * 64 + feat]);
    *(u16x8_t*)(W1b + (size_t)r * HIDDIM + t * 8) = o;
    return;
  }

  // ---------------- gcn branch ----------------
  const int wv = threadIdx.x >> 6, lane = threadIdx.x & 63;
  const int g = blockIdx.x * 4 + wv;
  char* my = smem + wv * 10240;
  unsigned int*   adjcnt = (unsigned int*)my;            // u32 [32][32], 4096B
  unsigned short* adjb   = (unsigned short*)my;          // bf16 [32][40] (overlays)
  unsigned short* outT   = (unsigned short*)my;          // bf16 [64][40] (overlays)
  unsigned short* hT     = (unsigned short*)(my + 5120); // bf16 [64][40]
  const int lr = lane & 15, lk = lane >> 4;

  const float* xg = x + (size_t)g * (NNODE * EMB);
  float4 xr[2][2][2];
  #pragma unroll
  for (int mt = 0; mt < 2; ++mt)
    #pragma unroll
    for (int kk = 0; kk < 2; ++kk) {
      const float* p = xg + (mt * 16 + lr) * EMB + kk * 32 + lk * 8;
      xr[mt][kk][0] = *(const float4*)p;
      xr[mt][kk][1] = *(const float4*)(p + 4);
    }

  int sl[4], dl[4];
  #pragma unroll
  for (int j = 0; j < 4; ++j) {
    sl[j] = ei[(size_t)g * EPG + j * 64 + lane] - g * NNODE;
    dl[j] = ei[(size_t)ETOT + (size_t)g * EPG + j * 64 + lane] - g * NNODE;
  }

  {
    uint4 z = {0u, 0u, 0u, 0u};
    #pragma unroll
    for (int i = 0; i < 4; ++i) *(uint4*)&adjcnt[lane * 16 + i * 4] = z;
  }
  asm volatile("" ::: "memory");
  #pragma unroll
  for (int j = 0; j < 4; ++j) atomicAdd(&adjcnt[dl[j] * 32 + sl[j]], 1u);
  asm volatile("" ::: "memory");

  const int rr = lane >> 1, hh = lane & 1;
  uint4 c[4];
  unsigned int cs = 0;
  #pragma unroll
  for (int i = 0; i < 4; ++i) {
    c[i] = *(const uint4*)&adjcnt[rr * 32 + hh * 16 + i * 4];
    cs += c[i].x + c[i].y + c[i].z + c[i].w;
  }
  cs += (unsigned int)__shfl_xor((int)cs, 1);
  const float dinvr = rsqrtf(1.0f + (float)cs);
  asm volatile("" ::: "memory");
  {
    float vals[16];
    #pragma unroll
    for (int i = 0; i < 4; ++i) {
      const unsigned int cc[4] = {c[i].x, c[i].y, c[i].z, c[i].w};
      #pragma unroll
      for (int e = 0; e < 4; ++e) {
        const int s = hh * 16 + i * 4 + e;
        const float ds = __shfl(dinvr, s * 2);
        const float cnt = (float)cc[e] + ((s == rr) ? 1.0f : 0.0f);
        vals[i * 4 + e] = cnt * dinvr * ds;
      }
    }
    union { unsigned int u[8]; u16x8_t v[2]; } pk;
    #pragma unroll
    for (int i = 0; i < 8; ++i) pk.u[i] = cvtpk(vals[2 * i], vals[2 * i + 1]);
    *(u16x8_t*)&adjb[rr * 40 + hh * 16]     = pk.v[0];
    *(u16x8_t*)&adjb[rr * 40 + hh * 16 + 8] = pk.v[1];
  }

  bf16x8_t xa[2][2];
  #pragma unroll
  for (int mt = 0; mt < 2; ++mt)
    #pragma unroll
    for (int kk = 0; kk < 2; ++kk) xa[mt][kk] = pack8(xr[mt][kk][0], xr[mt][kk][1]);
  f32x4_t hc[2][4];
  #pragma unroll
  for (int mt = 0; mt < 2; ++mt)
    #pragma unroll
    for (int nt = 0; nt < 4; ++nt) hc[mt][nt] = (f32x4_t){0.f, 0.f, 0.f, 0.f};
  #pragma unroll
  for (int nt = 0; nt < 4; ++nt)
    #pragma unroll
    for (int kk = 0; kk < 2; ++kk) {
      const float* p = Wc + (nt * 16 + lr) * EMB + kk * 32 + lk * 8;
      const bf16x8_t wb = pack8(*(const float4*)p, *(const float4*)(p + 4));
      #pragma unroll
      for (int mt = 0; mt < 2; ++mt)
        hc[mt][nt] = __builtin_amdgcn_mfma_f32_16x16x32_bf16(xa[mt][kk], wb, hc[mt][nt], 0, 0, 0);
    }
  #pragma unroll
  for (int mt = 0; mt < 2; ++mt)
    #pragma unroll
    for (int nt = 0; nt < 4; ++nt) {
      uint2 pk;
      pk.x = cvtpk(hc[mt][nt][0], hc[mt][nt][1]);
      pk.y = cvtpk(hc[mt][nt][2], hc[mt][nt][3]);
      *(uint2*)&hT[(nt * 16 + lr) * 40 + mt * 16 + lk * 4] = pk;
    }
  asm volatile("" ::: "memory");

  bf16x8_t aj[2];
  #pragma unroll
  for (int mt = 0; mt < 2; ++mt)
    aj[mt] = *(const bf16x8_t*)&adjb[(mt * 16 + lr) * 40 + lk * 8];
  f32x4_t oc[2][4];
  #pragma unroll
  for (int mt = 0; mt < 2; ++mt)
    #pragma unroll
    for (int nt = 0; nt < 4; ++nt) oc[mt][nt] = (f32x4_t){0.f, 0.f, 0.f, 0.f};
  #pragma unroll
  for (int nt = 0; nt < 4; ++nt) {
    const bf16x8_t hb = *(const bf16x8_t*)&hT[(nt * 16 + lr) * 40 + lk * 8];
    #pragma unroll
    for (int mt = 0; mt < 2; ++mt)
      oc[mt][nt] = __builtin_amdgcn_mfma_f32_16x16x32_bf16(aj[mt], hb, oc[mt][nt], 0, 0, 0);
  }
  asm volatile("" ::: "memory");

  #pragma unroll
  for (int nt = 0; nt < 4; ++nt) {
    const float bcv = bc[nt * 16 + lr];
    #pragma unroll
    for (int mt = 0; mt < 2; ++mt) {
      float v0 = fmaxf(oc[mt][nt][0] + bcv, 0.0f);
      float v1 = fmaxf(oc[mt][nt][1] + bcv, 0.0f);
      float v2 = fmaxf(oc[mt][nt][2] + bcv, 0.0f);
      float v3 = fmaxf(oc[mt][nt][3] + bcv, 0.0f);
      uint2 pk;
      pk.x = cvtpk(v0, v1);
      pk.y = cvtpk(v2, v3);
      *(uint2*)&outT[(nt * 16 + lr) * 40 + mt * 16 + lk * 4] = pk;
    }
  }
  asm volatile("" ::: "memory");

  unsigned short* og = abf + (size_t)g * HIDDIM;
  #pragma unroll
  for (int j = 0; j < 4; ++j) {
    const int e = lane * 8 + j * 512;
    const int feat = e >> 5, nb = e & 31;
    *(u16x8_t*)(og + e) = *(const u16x8_t*)&outT[feat * 40 + nb];
  }
}

// ---------------------------------------------------------------------------
// Kernel 2: lin1 GEMM + FUSED lin2 partial dots, NO ATOMICS.
// Round-14 schedule (best measured): 2-phase-per-tile, vmcnt(4/0) gates,
// drain-before-barrier, 129 barriers/block.
//   P0: read A0+B0+B1 (16 b128); stage A(next) h0+h1; lgkm0; barrier; 32 MFMA
//   P1: read A1 (8 b128);        stage B(next) h0+h1; lgkm0; vmcnt(4); barrier; 32 MFMA
// ---------------------------------------------------------------------------
__global__ __launch_bounds__(512, 1) void lin1_kernel(const unsigned short* __restrict__ A,
                                                      const unsigned short* __restrict__ Bw,
                                                      const float* __restrict__ b1,
                                                      const float* __restrict__ W2,
                                                      float2* __restrict__ part) {
  __shared__ __align__(16) unsigned short sh[65536];   // 128 KB

  const int bid = blockIdx.x;
  const int xcd = bid & 7;
  const int g = bid >> 3;                  // 0..63 within XCD
  const int bm = xcd * 8 + (g >> 3);
  const int bn = g & 7;

  const int tid = threadIdx.x;
  const int lane = tid & 63, w = tid >> 6;
  const int wm = w >> 2, wn = w & 3;       // 2 M-waves x 4 N-waves
  const int lr = lane & 15, lk = lane >> 4;

  const int r0 = tid >> 3;
  const int kge = ((((tid & 7) * 16) ^ ((r0 & 7) << 4)) >> 1);  // swizzled elem
  const unsigned short* gA = A  + (size_t)(bm * 256 + r0) * HIDDIM + kge;
  const unsigned short* gB = Bw + (size_t)(bn * 256 + r0) * HIDDIM + kge;

  auto stage = [&](const unsigned short* gb, int d, int mat, int half, int tile) {
    const unsigned short* s = gb + (size_t)(half * 128) * HIDDIM + tile * 64;
    unsigned short* l = &sh[d * 32768 + mat * 16384 + half * 8192 + tid * 8];
    GLDS(s, l);
    GLDS(s + (size_t)64 * HIDDIM, l + 4096);
  };

  const int arow = wm * 8192 + lr * 64;
  const int brow = 16384 + (wn >> 1) * 8192 + ((wn & 1) * 64 + lr) * 64;
  int eoff[2];
  eoff[0] = (lk * 8) ^ ((lr & 7) << 3);
  eoff[1] = (32 + lk * 8) ^ ((lr & 7) << 3);

  f32x4_t acc[8][4];
  #pragma unroll
  for (int i = 0; i < 8; ++i)
    #pragma unroll
    for (int j = 0; j < 4; ++j) acc[i][j] = (f32x4_t){0.f, 0.f, 0.f, 0.f};

  // ---- prologue: tile0 (A+B) -> dbuf0, tile1 B -> dbuf1; gate; barrier
  stage(gA, 0, 0, 0, 0); stage(gA, 0, 0, 1, 0);
  stage(gB, 0, 1, 0, 0); stage(gB, 0, 1, 1, 0);
  stage(gB, 1, 1, 0, 1); stage(gB, 1, 1, 1, 1);
  asm volatile("s_waitcnt vmcnt(4)" ::: "memory");
  __builtin_amdgcn_sched_barrier(0);
  __builtin_amdgcn_s_barrier();

  bf16x8_t af[4][2], bv0[2][2], bv1[2][2];

  for (int it = 0; it < 16; ++it) {
    const int o = 2 * it + 1;
    const bool more = (it < 15);

    #pragma unroll
    for (int half = 0; half < 2; ++half) {     // half 0: dbuf0 (tile 2it), 1: dbuf1
      const int dof = half * 32768;

      // ---- P0: read A0 quadrant + B0 + B1; stage A(next) h0+h1
      #pragma unroll
      for (int mi = 0; mi < 4; ++mi) {
        af[mi][0] = *(const bf16x8_t*)&sh[dof + arow + mi * 1024 + eoff[0]];
        af[mi][1] = *(const bf16x8_t*)&sh[dof + arow + mi * 1024 + eoff[1]];
      }
      #pragma unroll
      for (int ni = 0; ni < 2; ++ni) {
        bv0[ni][0] = *(const bf16x8_t*)&sh[dof + brow + ni * 1024 + eoff[0]];
        bv0[ni][1] = *(const bf16x8_t*)&sh[dof + brow + ni * 1024 + eoff[1]];
        bv1[ni][0] = *(const bf16x8_t*)&sh[dof + brow + (ni + 2) * 1024 + eoff[0]];
        bv1[ni][1] = *(const bf16x8_t*)&sh[dof + brow + (ni + 2) * 1024 + eoff[1]];
      }
      if (half == 0)      { stage(gA, 1, 0, 0, o);     stage(gA, 1, 0, 1, o); }
      else if (more)      { stage(gA, 0, 0, 0, o + 1); stage(gA, 0, 0, 1, o + 1); }
      asm volatile("s_waitcnt lgkmcnt(0)" ::: "memory");
      __builtin_amdgcn_sched_barrier(0);
      __builtin_amdgcn_s_barrier();
      __builtin_amdgcn_s_setprio(1);
      #pragma unroll
      for (int kk = 0; kk < 2; ++kk)
        #pragma unroll
        for (int mi = 0; mi < 4; ++mi)
          #pragma unroll
          for (int ni = 0; ni < 2; ++ni) {
            acc[mi][ni]     = __builtin_amdgcn_mfma_f32_16x16x32_bf16(af[mi][kk], bv0[ni][kk], acc[mi][ni], 0, 0, 0);
            acc[mi][ni + 2] = __builtin_amdgcn_mfma_f32_16x16x32_bf16(af[mi][kk], bv1[ni][kk], acc[mi][ni + 2], 0, 0, 0);
          }
      __builtin_amdgcn_s_setprio(0);

      // ---- P1: read A1 quadrant; stage B(next) h0+h1; gate; barrier
      #pragma unroll
      for (int mi = 0; mi < 4; ++mi) {
        af[mi][0] = *(const bf16x8_t*)&sh[dof + arow + (mi + 4) * 1024 + eoff[0]];
        af[mi][1] = *(const bf16x8_t*)&sh[dof + arow + (mi + 4) * 1024 + eoff[1]];
      }
      if (more) {
        const int tgt = (half == 0) ? (o + 1) : (o + 2);
        stage(gB, half, 1, 0, tgt);
        stage(gB, half, 1, 1, tgt);
      }
      asm volatile("s_waitcnt lgkmcnt(0)" ::: "memory");
      if (more) { asm volatile("s_waitcnt vmcnt(4)" ::: "memory"); }
      else      { asm volatile("s_waitcnt vmcnt(0)" ::: "memory"); }
      __builtin_amdgcn_sched_barrier(0);
      __builtin_amdgcn_s_barrier();
      __builtin_amdgcn_s_setprio(1);
      #pragma unroll
      for (int kk = 0; kk < 2; ++kk)
        #pragma unroll
        for (int mi = 0; mi < 4; ++mi)
          #pragma unroll
          for (int ni = 0; ni < 2; ++ni) {
            acc[mi + 4][ni]     = __builtin_amdgcn_mfma_f32_16x16x32_bf16(af[mi][kk], bv0[ni][kk], acc[mi + 4][ni], 0, 0, 0);
            acc[mi + 4][ni + 2] = __builtin_amdgcn_mfma_f32_16x16x32_bf16(af[mi][kk], bv1[ni][kk], acc[mi + 4][ni + 2], 0, 0, 0);
          }
      __builtin_amdgcn_s_setprio(0);
    }
  }

  // ---- fused epilogue (no atomics): relu(acc+b1).W2 -> lr shfl-reduce ->
  // cross-wn LDS reduce -> coalesced float2 partial store per block.
  const int ccol0 = bn * 256 + wn * 64 + lr;
  float b1v[4], w2a[4], w2b[4];
  #pragma unroll
  for (int ni = 0; ni < 4; ++ni) {
    b1v[ni] = b1[ccol0 + ni * 16];
    w2a[ni] = W2[ccol0 + ni * 16];
    w2b[ni] = W2[HIDDIM + ccol0 + ni * 16];
  }
  float2* pl = (float2*)sh;   // [256][4] float2 = 8KB; safe overlay
  #pragma unroll
  for (int mi = 0; mi < 8; ++mi)
    #pragma unroll
    for (int r = 0; r < 4; ++r) {
      float s0 = 0.0f, s1 = 0.0f;
      #pragma unroll
      for (int ni = 0; ni < 4; ++ni) {
        const float v = fmaxf(acc[mi][ni][r] + b1v[ni], 0.0f);
        s0 = fmaf(v, w2a[ni], s0);
        s1 = fmaf(v, w2b[ni], s1);
      }
      #pragma unroll
      for (int off = 1; off < 16; off <<= 1) {
        s0 += __shfl_xor(s0, off);
        s1 += __shfl_xor(s1, off);
      }
      if (lr == 0) {
        const int rowLocal = wm * 128 + mi * 16 + lk * 4 + r;
        float2 v2; v2.x = s0; v2.y = s1;
        pl[rowLocal * 4 + wn] = v2;
      }
    }
  __syncthreads();
  if (tid < 256) {
    const float2 p0 = pl[tid * 4 + 0];
    const float2 p1 = pl[tid * 4 + 1];
    const float2 p2 = pl[tid * 4 + 2];
    const float2 p3 = pl[tid * 4 + 3];
    float2 o;
    o.x = (p0.x + p1.x) + (p2.x + p3.x);
    o.y = (p0.y + p1.y) + (p2.y + p3.y);
    part[(size_t)bn * NGRAPH + bm * 256 + tid] = o;
  }
}

// ---------------------------------------------------------------------------
// Kernel 3: sum 8 bn-partials + b2 -> softmax
// ---------------------------------------------------------------------------
__global__ __launch_bounds__(256) void softmax_kernel(const float2* __restrict__ part,
                                                      const float* __restrict__ b2,
                                                      float* __restrict__ out) {
  const int i = blockIdx.x * 256 + threadIdx.x;   // graph id
  float s0 = 0.0f, s1 = 0.0f;
  #pragma unroll
  for (int bn = 0; bn < 8; ++bn) {
    const float2 p = part[(size_t)bn * NGRAPH + i];
    s0 += p.x; s1 += p.y;
  }
  const float l0 = s0 + b2[0];
  const float l1 = s1 + b2[1];
  const float mx = fmaxf(l0, l1);
  const float e0 = expf(l0 - mx);
  const float e1 = expf(l1 - mx);
  const float inv = 1.0f / (e0 + e1);
  float2 o;
  o.x = e0 * inv;
  o.y = e1 * inv;
  *((float2*)out + i) = o;
}

// ---------------------------------------------------------------------------
extern "C" void kernel_launch(void* const* d_in, const int* in_sizes, int n_in,
                              void* d_out, int out_size, void* d_ws, size_t ws_size,
                              hipStream_t stream) {
  const float* x  = (const float*)d_in[0];
  const float* Wc = (const float*)d_in[1];
  const float* bc = (const float*)d_in[2];
  const float* W1 = (const float*)d_in[3];
  const float* b1 = (const float*)d_in[4];
  const float* W2 = (const float*)d_in[5];
  const float* b2 = (const float*)d_in[6];
  const int* ei   = (const int*)d_in[7];

  // workspace: [0,64MB) Abf bf16 (graph-transposed); [64,72MB) W1bf bf16
  // (col-permuted); [72MB, +1MB) part fp32x2 [8][16384]
  unsigned short* Abf  = (unsigned short*)d_ws;
  unsigned short* W1bf = (unsigned short*)((char*)d_ws + (size_t)67108864);
  float2*         part = (float2*)((char*)d_ws + (size_t)75497472);

  front_kernel<<<dim3(6144), dim3(256), 0, stream>>>(x, Wc, bc, ei, Abf, W1, W1bf);
  lin1_kernel<<<dim3(512), dim3(512), 0, stream>>>(Abf, W1bf, b1, W2, part);
  softmax_kernel<<<dim3(64), dim3(256), 0, stream>>>(part, b2, (float*)d_out);
}